// Round 1
// baseline (585.356 us; speedup 1.0000x reference)
//
#include <hip/hip_runtime.h>
#include <hip/hip_fp16.h>

typedef _Float16 half8 __attribute__((ext_vector_type(8)));
typedef _Float16 half4 __attribute__((ext_vector_type(4)));
typedef float floatx16 __attribute__((ext_vector_type(16)));

// async global->LDS, 16B per lane; LDS dest is wave-uniform base + lane*16
#define GLDS16(g, l)                                                           \
  __builtin_amdgcn_global_load_lds(                                            \
      (const __attribute__((address_space(1))) void*)(g),                      \
      (__attribute__((address_space(3))) void*)(l), 16, 0, 0)

// ---------------------------------------------------------------------------
// Fused prep: W_eff = sum_k mw[k]*(mu[k]+exp(0.5*lv[k])*n[k]) (fp16 out),
// bias_eff (fp32), and x fp32->fp16 cvt — all in ONE launch.
// R1: restructured for MLP — all 16 float4 loads issued before any FMA
// (old version had VGPR=28 -> loads serialized -> 1.86 TB/s). 32B/stream
// per thread; heavy W-prep blocks first in grid to remove the tail.
// ---------------------------------------------------------------------------
__device__ inline void mix_coeffs(const float* lv, const float* ml,
                                  float* cmu, float* cn) {
  float m0 = ml[0], m1 = ml[1], m2 = ml[2], m3 = ml[3];
  float mx = fmaxf(fmaxf(m0, m1), fmaxf(m2, m3));
  float e0 = __expf(m0 - mx), e1 = __expf(m1 - mx);
  float e2 = __expf(m2 - mx), e3 = __expf(m3 - mx);
  float inv = 1.0f / (e0 + e1 + e2 + e3);
  cmu[0] = e0 * inv; cmu[1] = e1 * inv; cmu[2] = e2 * inv; cmu[3] = e3 * inv;
  cn[0] = cmu[0] * __expf(0.5f * lv[0]);
  cn[1] = cmu[1] * __expf(0.5f * lv[1]);
  cn[2] = cmu[2] * __expf(0.5f * lv[2]);
  cn[3] = cmu[3] * __expf(0.5f * lv[3]);
}

__device__ inline void do_prep_w(const float* __restrict__ mu,
                                 const float* __restrict__ nz,
                                 const float* lv, const float* ml,
                                 _Float16* __restrict__ out, int count,
                                 int bid) {
  float cmu[4], cn[4];
  mix_coeffs(lv, ml, cmu, cn);
  long i = (long)bid * 2048 + threadIdx.x * 8;  // 8 floats/thread/stream
  // issue ALL 16 independent loads back-to-back (keep them in flight)
  float4 a0 = *(const float4*)(mu + 0L * count + i);
  float4 a0b = *(const float4*)(mu + 0L * count + i + 4);
  float4 a1 = *(const float4*)(mu + 1L * count + i);
  float4 a1b = *(const float4*)(mu + 1L * count + i + 4);
  float4 a2 = *(const float4*)(mu + 2L * count + i);
  float4 a2b = *(const float4*)(mu + 2L * count + i + 4);
  float4 a3 = *(const float4*)(mu + 3L * count + i);
  float4 a3b = *(const float4*)(mu + 3L * count + i + 4);
  float4 b0 = *(const float4*)(nz + 0L * count + i);
  float4 b0b = *(const float4*)(nz + 0L * count + i + 4);
  float4 b1 = *(const float4*)(nz + 1L * count + i);
  float4 b1b = *(const float4*)(nz + 1L * count + i + 4);
  float4 b2 = *(const float4*)(nz + 2L * count + i);
  float4 b2b = *(const float4*)(nz + 2L * count + i + 4);
  float4 b3 = *(const float4*)(nz + 3L * count + i);
  float4 b3b = *(const float4*)(nz + 3L * count + i + 4);

  float r0 = cmu[0]*a0.x + cn[0]*b0.x + cmu[1]*a1.x + cn[1]*b1.x
           + cmu[2]*a2.x + cn[2]*b2.x + cmu[3]*a3.x + cn[3]*b3.x;
  float r1 = cmu[0]*a0.y + cn[0]*b0.y + cmu[1]*a1.y + cn[1]*b1.y
           + cmu[2]*a2.y + cn[2]*b2.y + cmu[3]*a3.y + cn[3]*b3.y;
  float r2 = cmu[0]*a0.z + cn[0]*b0.z + cmu[1]*a1.z + cn[1]*b1.z
           + cmu[2]*a2.z + cn[2]*b2.z + cmu[3]*a3.z + cn[3]*b3.z;
  float r3 = cmu[0]*a0.w + cn[0]*b0.w + cmu[1]*a1.w + cn[1]*b1.w
           + cmu[2]*a2.w + cn[2]*b2.w + cmu[3]*a3.w + cn[3]*b3.w;
  float r4 = cmu[0]*a0b.x + cn[0]*b0b.x + cmu[1]*a1b.x + cn[1]*b1b.x
           + cmu[2]*a2b.x + cn[2]*b2b.x + cmu[3]*a3b.x + cn[3]*b3b.x;
  float r5 = cmu[0]*a0b.y + cn[0]*b0b.y + cmu[1]*a1b.y + cn[1]*b1b.y
           + cmu[2]*a2b.y + cn[2]*b2b.y + cmu[3]*a3b.y + cn[3]*b3b.y;
  float r6 = cmu[0]*a0b.z + cn[0]*b0b.z + cmu[1]*a1b.z + cn[1]*b1b.z
           + cmu[2]*a2b.z + cn[2]*b2b.z + cmu[3]*a3b.z + cn[3]*b3b.z;
  float r7 = cmu[0]*a0b.w + cn[0]*b0b.w + cmu[1]*a1b.w + cn[1]*b1b.w
           + cmu[2]*a2b.w + cn[2]*b2b.w + cmu[3]*a3b.w + cn[3]*b3b.w;

  half8 h = {(_Float16)r0, (_Float16)r1, (_Float16)r2, (_Float16)r3,
             (_Float16)r4, (_Float16)r5, (_Float16)r6, (_Float16)r7};
  *(half8*)(out + i) = h;
}

__device__ inline void do_prep_b(const float* __restrict__ bmu,
                                 const float* __restrict__ bn,
                                 const float* lv, const float* ml,
                                 float* __restrict__ out, int O, int bid) {
  float cmu[4], cn[4];
  mix_coeffs(lv, ml, cmu, cn);
  int i = bid * 256 + threadIdx.x;
  if (i >= O) return;
  float r = 0.f;
#pragma unroll
  for (int k = 0; k < 4; ++k)
    r += cmu[k] * bmu[k * O + i] + cn[k] * bn[k * O + i];
  out[i] = r;
}

__device__ inline void do_cvt(const float* __restrict__ in,
                              _Float16* __restrict__ out, int bid) {
  long i = (long)bid * 2048 + threadIdx.x * 8;
  float4 v0 = *(const float4*)(in + i);
  float4 v1 = *(const float4*)(in + i + 4);
  half8 h = {(_Float16)v0.x, (_Float16)v0.y, (_Float16)v0.z, (_Float16)v0.w,
             (_Float16)v1.x, (_Float16)v1.y, (_Float16)v1.z, (_Float16)v1.w};
  *(half8*)(out + i) = h;
}

struct PrepArgs {
  const float* x; _Float16* x16;
  const float* wmu0; const float* wn0; const float* wlv0; const float* ml0; _Float16* W0;
  const float* wmu1; const float* wn1; const float* wlv1; const float* ml1; _Float16* W1;
  const float* wmu2; const float* wn2; const float* wlv2; const float* ml2; _Float16* W2;
  const float* bmu0; const float* bn0; const float* blv0; float* b0;
  const float* bmu1; const float* bn1; const float* blv1; float* b1;
  const float* bmu2; const float* bn2; const float* blv2; float* b2;
};

// grid = 2048(W0) + 2048(W1) + 1024(W2) + 8192(cvt) + 8 + 8 + 4 = 13332
__global__ __launch_bounds__(256) void prep_all(PrepArgs a) {
  int b = blockIdx.x;
  if (b < 2048) { do_prep_w(a.wmu0, a.wn0, a.wlv0, a.ml0, a.W0, 2048 * 2048, b); return; }
  b -= 2048;
  if (b < 2048) { do_prep_w(a.wmu1, a.wn1, a.wlv1, a.ml1, a.W1, 2048 * 2048, b); return; }
  b -= 2048;
  if (b < 1024) { do_prep_w(a.wmu2, a.wn2, a.wlv2, a.ml2, a.W2, 1024 * 2048, b); return; }
  b -= 1024;
  if (b < 8192) { do_cvt(a.x, a.x16, b); return; }
  b -= 8192;
  if (b < 8) { do_prep_b(a.bmu0, a.bn0, a.blv0, a.ml0, a.b0, 2048, b); return; }
  b -= 8;
  if (b < 8) { do_prep_b(a.bmu1, a.bn1, a.blv1, a.ml1, a.b1, 2048, b); return; }
  b -= 8;
  do_prep_b(a.bmu2, a.bn2, a.blv2, a.ml2, a.b2, 1024, b);
}

// ---------------------------------------------------------------------------
// GEMM: C[M,N] = act(A[M,K] * B[N,K]^T + bias), fp16 in, 32x32x16 MFMA.
// R1: 2-phase double-buffered pipeline (catalog T3-min recipe): stage tile
// k+1 into buf^1 BEFORE computing tile k from buf; ONE __syncthreads per
// K-step (its vmcnt(0)+lgkmcnt(0) drain is exactly the 2-phase semantic:
// prefetch latency hides under ds_read+MFMA of the current tile).
// gemm0/1: BM=BN=256, 8 waves (2x4), wave tile 128x64 -> acc[4][2];
//          LDS = 2 x (32KB A + 32KB B) = 128 KiB (gfx950 allows 160).
// gemm2:   BM=BN=128, 4 waves (2x2), wave tile 64x64 -> acc[2][2]; 64 KiB.
//
// LDS layout per buffer: row-major rows of 8 granules (16B; BK=64 fp16 =
// 128B/row), XOR swizzle: LDS(r,pos) holds global granule gc = pos^(r&7).
//  - staging GLDS (lane-linear dest): coalesced, permuted within 128B row.
//  - fragment read (lane l: row=l&31 within 32-tile, g=s*2+(l>>5)):
//    pos=g^(row&7); 0 bank conflicts (verified in earlier rounds).
// A-frag (32x32x16): lane holds A[m=l&31][k=(l>>5)*8+j], j=0..7.
// C/D layout (m74/m101): col=lane&31, row=(reg&3)+8*(reg>>2)+4*(lane>>5).
// ---------------------------------------------------------------------------
template <int BM, int BN, int WM, int WN, bool RELU, bool OUT_HALF>
__global__ __launch_bounds__((BM / WM) * (BN / WN) * 64, 2) void gemm2ph(
    const _Float16* __restrict__ A, const _Float16* __restrict__ B,
    const float* __restrict__ bias, void* __restrict__ Cout,
    int M, int N, int K) {
  constexpr int NWC = BN / WN;
  constexpr int NWR = BM / WM;
  constexpr int NW = NWC * NWR;
  constexpr int NT = NW * 64;
  constexpr int MT = WM / 32;
  constexpr int CT = WN / 32;
  constexpr int GA = BM * 8 / NT;  // GLDS16 per thread for A per K-step
  constexpr int GB = BN * 8 / NT;

  __shared__ _Float16 sA[2][BM * 64];
  __shared__ _Float16 sB[2][BN * 64];

  const int t = threadIdx.x;
  const int l = t & 63;
  const int w = t >> 6;
  const int wr = w / NWC;
  const int wc = w % NWC;
  const long rowBlock = (long)blockIdx.x * BM;
  const long colBlock = (long)blockIdx.y * BN;

  floatx16 acc[MT][CT] = {};

  const _Float16* ga[GA];
  const _Float16* gb[GB];
#pragma unroll
  for (int j = 0; j < GA; ++j) {
    int p = j * NT + t;
    int r = p >> 3, pos = p & 7;
    int gc = pos ^ (r & 7);
    ga[j] = A + (rowBlock + r) * (long)K + gc * 8;
  }
#pragma unroll
  for (int j = 0; j < GB; ++j) {
    int p = j * NT + t;
    int r = p >> 3, pos = p & 7;
    int gc = pos ^ (r & 7);
    gb[j] = B + (colBlock + r) * (long)K + gc * 8;
  }

  const int rm = l & 31;
  const int kh = l >> 5;
  const int sw = rm & 7;

  // prologue: stage tile 0 into buf 0
#pragma unroll
  for (int j = 0; j < GA; ++j)
    GLDS16(ga[j], (char*)sA[0] + w * 1024 + j * (NT * 16));
#pragma unroll
  for (int j = 0; j < GB; ++j)
    GLDS16(gb[j], (char*)sB[0] + w * 1024 + j * (NT * 16));
  __syncthreads();

  int cur = 0;
  for (int k0 = 0; k0 < K; k0 += 64) {
    // phase 1: issue next tile's stage (async, overlaps with compute below)
    if (k0 + 64 < K) {
      const int nxt = cur ^ 1;
#pragma unroll
      for (int j = 0; j < GA; ++j)
        GLDS16(ga[j] + k0 + 64, (char*)sA[nxt] + w * 1024 + j * (NT * 16));
#pragma unroll
      for (int j = 0; j < GB; ++j)
        GLDS16(gb[j] + k0 + 64, (char*)sB[nxt] + w * 1024 + j * (NT * 16));
    }
    // phase 2: compute current tile
#pragma unroll
    for (int s = 0; s < 4; ++s) {  // four K=16 MFMA steps per BK=64
      const int pos = (s * 2 + kh) ^ sw;
      half8 af[MT], bf[CT];
#pragma unroll
      for (int rt = 0; rt < MT; ++rt)
        af[rt] = *(const half8*)((const char*)sA[cur] +
                                 ((wr * WM + rt * 32 + rm) * 128 + pos * 16));
#pragma unroll
      for (int ct = 0; ct < CT; ++ct)
        bf[ct] = *(const half8*)((const char*)sB[cur] +
                                 ((wc * WN + ct * 32 + rm) * 128 + pos * 16));
#pragma unroll
      for (int rt = 0; rt < MT; ++rt)
#pragma unroll
        for (int ct = 0; ct < CT; ++ct)
          acc[rt][ct] = __builtin_amdgcn_mfma_f32_32x32x16_f16(
              af[rt], bf[ct], acc[rt][ct], 0, 0, 0);
    }
    // one barrier per K-step: drains lgkmcnt (reads of buf[cur] done before
    // it is overwritten next iter) and vmcnt (prefetch into buf[nxt] landed)
    __syncthreads();
    cur ^= 1;
  }

  // epilogue
  const int cl = l & 31;
  const int rh = (l >> 5) * 4;
#pragma unroll
  for (int rt = 0; rt < MT; ++rt) {
#pragma unroll
    for (int ct = 0; ct < CT; ++ct) {
      const long colg = colBlock + wc * WN + ct * 32 + cl;
      const float bv = bias[colg];
#pragma unroll
      for (int reg = 0; reg < 16; ++reg) {
        const int rowin = (reg & 3) + 8 * (reg >> 2) + rh;
        const long rowg = rowBlock + wr * WM + rt * 32 + rowin;
        float v = acc[rt][ct][reg] + bv;
        if (RELU) v = fmaxf(v, 0.0f);
        if (OUT_HALF)
          ((_Float16*)Cout)[rowg * N + colg] = (_Float16)v;
        else
          ((float*)Cout)[rowg * N + colg] = v;
      }
    }
  }
}

// ---------------------------------------------------------------------------
// Row softmax over N=1024, one block per row, one float4 per thread
// ---------------------------------------------------------------------------
__global__ __launch_bounds__(256) void softmax_rows(float* __restrict__ io) {
  const int N = 1024;
  float* p = io + (long)blockIdx.x * N;
  int t = threadIdx.x;
  int w = t >> 6;
  float4 v = ((const float4*)p)[t];
  float m = fmaxf(fmaxf(v.x, v.y), fmaxf(v.z, v.w));
#pragma unroll
  for (int off = 32; off > 0; off >>= 1) m = fmaxf(m, __shfl_xor(m, off));
  __shared__ float red[8];
  if ((t & 63) == 0) red[w] = m;
  __syncthreads();
  m = fmaxf(fmaxf(red[0], red[1]), fmaxf(red[2], red[3]));
  float4 e;
  e.x = __expf(v.x - m); e.y = __expf(v.y - m);
  e.z = __expf(v.z - m); e.w = __expf(v.w - m);
  float s = e.x + e.y + e.z + e.w;
#pragma unroll
  for (int off = 32; off > 0; off >>= 1) s += __shfl_xor(s, off);
  if ((t & 63) == 0) red[4 + w] = s;
  __syncthreads();
  s = red[4] + red[5] + red[6] + red[7];
  float inv = 1.0f / s;
  float4 o = {e.x * inv, e.y * inv, e.z * inv, e.w * inv};
  ((float4*)p)[t] = o;
}

// ---------------------------------------------------------------------------
extern "C" void kernel_launch(void* const* d_in, const int* in_sizes, int n_in,
                              void* d_out, int out_size, void* d_ws,
                              size_t ws_size, hipStream_t stream) {
  char* ws = (char*)d_ws;
  _Float16* x16 = (_Float16*)(ws);              // 33,554,432 B (reused as h1)
  _Float16* h0  = (_Float16*)(ws + 33554432);   // 33,554,432 B
  _Float16* W0  = (_Float16*)(ws + 67108864);   //  8,388,608 B
  _Float16* W1  = (_Float16*)(ws + 75497472);   //  8,388,608 B
  _Float16* W2  = (_Float16*)(ws + 83886080);   //  4,194,304 B
  float* b0 = (float*)(ws + 88080384);          //  8 KB
  float* b1 = (float*)(ws + 88088576);          //  8 KB
  float* b2 = (float*)(ws + 88096768);          //  4 KB

  PrepArgs a;
  a.x = (const float*)d_in[0]; a.x16 = x16;
  a.wmu0 = (const float*)d_in[1];  a.bmu0 = (const float*)d_in[2];
  a.wlv0 = (const float*)d_in[3];  a.blv0 = (const float*)d_in[4];
  a.ml0  = (const float*)d_in[5];
  a.wn0  = (const float*)d_in[6];  a.bn0  = (const float*)d_in[7];
  a.wmu1 = (const float*)d_in[8];  a.bmu1 = (const float*)d_in[9];
  a.wlv1 = (const float*)d_in[10]; a.blv1 = (const float*)d_in[11];
  a.ml1  = (const float*)d_in[12];
  a.wn1  = (const float*)d_in[13]; a.bn1  = (const float*)d_in[14];
  a.wmu2 = (const float*)d_in[15]; a.bmu2 = (const float*)d_in[16];
  a.wlv2 = (const float*)d_in[17]; a.blv2 = (const float*)d_in[18];
  a.ml2  = (const float*)d_in[19];
  a.wn2  = (const float*)d_in[20]; a.bn2  = (const float*)d_in[21];
  a.W0 = W0; a.W1 = W1; a.W2 = W2; a.b0 = b0; a.b1 = b1; a.b2 = b2;

  prep_all<<<13332, 256, 0, stream>>>(a);

  // gemm0: [8192,2048] = x16 @ W0^T   (256x256 tile, 512 thr, 128 KiB LDS)
  gemm2ph<256, 256, 128, 64, true, true><<<dim3(32, 8), 512, 0, stream>>>(
      x16, W0, b0, h0, 8192, 2048, 2048);
  // gemm1: [8192,2048] = h0 @ W1^T
  gemm2ph<256, 256, 128, 64, true, true><<<dim3(32, 8), 512, 0, stream>>>(
      h0, W1, b1, x16, 8192, 2048, 2048);
  // gemm2: [8192,1024] = h1 @ W2^T    (128x128 tile, 256 thr, 64 KiB LDS)
  gemm2ph<128, 128, 64, 64, false, false><<<dim3(64, 8), 256, 0, stream>>>(
      x16, W2, b2, d_out, 8192, 1024, 2048);
  softmax_rows<<<8192, 256, 0, stream>>>((float*)d_out);
}